// Round 11
// baseline (536.123 us; speedup 1.0000x reference)
//
#include <hip/hip_runtime.h>
#include <hip/hip_bf16.h>

#define NN 100000
#define NE 1250000
#define DD 64
#define RR 16
#define NTILE 6250        // NN/16 dst-tiles
#define NBINS 100000      // (dst>>4)*16 + rel
#define NBLK_SCAN 391     // ceil(NBINS/256)
#define XCAP 320          // staged x rows per tile (mean 200, sigma ~14)
#define EBCAP 512

typedef __attribute__((ext_vector_type(8))) short s16x8;
typedef __attribute__((ext_vector_type(4))) float f32x4;

static __device__ __forceinline__ unsigned short f2bf(float v) {
    __hip_bfloat16 h = __float2bfloat16(v);
    return __builtin_bit_cast(unsigned short, h);
}
static __device__ __forceinline__ unsigned int pack2(float a, float b) {
    return ((unsigned int)f2bf(b) << 16) | (unsigned int)f2bf(a);
}

// ---------------- sort edges by (dst-tile, rel): counting sort, 100k bins ----------------

__global__ void hist_key(const int* __restrict__ dst, const int* __restrict__ et,
                         int* __restrict__ cnt) {
    int e = blockIdx.x * 256 + threadIdx.x;
    if (e < NE) atomicAdd(&cnt[(dst[e] >> 4) * 16 + et[e]], 1);
}

__global__ __launch_bounds__(256) void scan1(const int* __restrict__ cnt,
                                             int* __restrict__ rp, int* __restrict__ part) {
    __shared__ int s[256];
    int i = blockIdx.x * 256 + threadIdx.x;
    int v = (i < NBINS) ? cnt[i] : 0;
    s[threadIdx.x] = v;
    __syncthreads();
    for (int off = 1; off < 256; off <<= 1) {
        int t = (threadIdx.x >= off) ? s[threadIdx.x - off] : 0;
        __syncthreads();
        s[threadIdx.x] += t;
        __syncthreads();
    }
    if (i < NBINS) rp[i] = s[threadIdx.x] - v;        // exclusive
    if (threadIdx.x == 255) part[blockIdx.x] = s[255];
}

__global__ void scan2(int* __restrict__ part, int* __restrict__ rp) {
    __shared__ int s[NBLK_SCAN];
    if (threadIdx.x < NBLK_SCAN) s[threadIdx.x] = part[threadIdx.x];
    __syncthreads();
    if (threadIdx.x == 0) {
        int acc = 0;
        for (int b = 0; b < NBLK_SCAN; ++b) { int t = s[b]; s[b] = acc; acc += t; }
        rp[NBINS] = NE;
    }
    __syncthreads();
    if (threadIdx.x < NBLK_SCAN) part[threadIdx.x] = s[threadIdx.x];
}

__global__ void scan3(int* __restrict__ rp, const int* __restrict__ part, int* __restrict__ cur) {
    int i = blockIdx.x * 256 + threadIdx.x;
    if (i < NBINS) {
        int v = rp[i] + part[blockIdx.x];
        rp[i] = v;
        cur[i] = v;
    }
}

// ep[p] = src | (dst&15)<<20
__global__ void scatter_key(const int* __restrict__ src, const int* __restrict__ dst,
                            const int* __restrict__ et, int* __restrict__ cur,
                            unsigned int* __restrict__ ep) {
    int e = blockIdx.x * 256 + threadIdx.x;
    if (e >= NE) return;
    int d = dst[e];
    int p = atomicAdd(&cur[(d >> 4) * 16 + et[e]], 1);
    ep[p] = (unsigned int)src[e] | ((unsigned int)(d & 15) << 20);
}

// ---------------- precision prep ----------------

__global__ void prep_w2(const float* __restrict__ W1, const float* __restrict__ sw1,
                        const float* __restrict__ W2, const float* __restrict__ sw2,
                        unsigned short* __restrict__ wt) {
    int i = blockIdx.x * 256 + threadIdx.x;
    if (i >= 2 * 17 * DD * DD) return;
    int d = i & 63;
    int o = (i >> 6) & 63;
    int p = (i >> 12) % 17;
    int l = i / (17 * DD * DD);
    const float* srcp;
    if (p < 16) srcp = (l ? W2 : W1) + p * DD * DD;
    else        srcp = (l ? sw2 : sw1);
    wt[i] = f2bf(srcp[d * DD + o]);
}

__global__ void prep_x2(const float* __restrict__ x, unsigned short* __restrict__ xb) {
    int i = blockIdx.x * blockDim.x + threadIdx.x;
    if (i < NN * DD) xb[i] = f2bf(x[i]);
}

// ---------------- fused layer ----------------
// Block = 16-dst tile. Phase 1: stage edge list + ALL x-rows into LDS with
// fully parallel independent gathers (k-permuted so each MFMA A-frag is one
// contiguous 16B ds_read). Phase 2: wave w owns o-block w, runs all 17 planes
// from LDS (short chains, no cross-wave reduction). Indicator-MFMA per-dst sum
// as in R10 (verified). Epilogue via padded LDS tile -> coalesced stores.
__global__ __launch_bounds__(256) void fused_layer(
    const unsigned short* __restrict__ xb,   // [N][64] bf16 layer input
    const unsigned short* __restrict__ wt,   // [17][64][64] bf16 (o-major, d inner)
    const int* __restrict__ rp,              // [NBINS+1]
    const unsigned int* __restrict__ ep,     // [E] src | dstloc<<20
    const float* __restrict__ bias,
    const float* __restrict__ xres,          // fp32 residual or nullptr
    unsigned short* __restrict__ outb,       // bf16 out (layer 1) or nullptr
    float* __restrict__ outf)                // fp32 out (layer 2) or nullptr
{
    __shared__ unsigned short xs[XCAP * 72]; // 46080 B, stride 144 B, k-permuted
    __shared__ unsigned int eb[EBCAP];       // 2048 B
    __shared__ float osg[16 * 65];           // 4160 B
    __shared__ int rps[17];
    const int tid  = threadIdx.x;
    const int wid  = tid >> 6;               // o-block
    const int lane = tid & 63;
    const int c = lane & 15;
    const int q = lane >> 4;
    const int tile = blockIdx.x;
    const int n0 = tile * 16;

    if (tid < 17) rps[tid] = rp[tile * 16 + tid];
    __syncthreads();
    const int e0 = rps[0];
    const int cnt = rps[16] - e0;
    const bool useLds = (cnt <= XCAP);
    const int nst = min(cnt, EBCAP);

    for (int i = tid; i < nst; i += 256) eb[i] = ep[e0 + i];
    __syncthreads();

    if (useLds) {
        // stage x rows: piece p = (row, j); global k-bytes j*16 -> LDS (j&3)*32+(j>>2)*16
        const int npc = cnt * 8;
        for (int p = tid; p < npc; p += 256) {
            const int row = p >> 3, j = p & 7;
            const int s = (int)(eb[row] & 0xFFFFF);
            s16x8 v = *(const s16x8*)(xb + (size_t)s * DD + j * 8);
            *(s16x8*)(xs + row * 72 + (j & 3) * 16 + (j >> 2) * 8) = v;
        }
    }
    __syncthreads();

    f32x4 D = {0.f, 0.f, 0.f, 0.f};
    const int nstm1 = (cnt > 0) ? (cnt - 1) : 0;

    for (int r = 0; r < 16; ++r) {
        const int s0 = rps[r];
        const int s1 = (r < 15) ? rps[r + 1] : (e0 + cnt);
        if (s0 >= s1) continue;
        // hoist this wave's W rows for plane r
        const unsigned short* wrow = wt + r * (DD * DD) + (wid * 16 + c) * DD + q * 8;
        s16x8 w0 = *(const s16x8*)(wrow);
        s16x8 w1 = *(const s16x8*)(wrow + 32);

        for (int b0 = s0; b0 < s1; b0 += 32) {
            const int lb = b0 - e0;
            const int rem = s1 - b0;
            const bool hasB = (rem > 16);

            s16x8 aA0, aA1, aB0, aB1;
            s16x8 a2;
            if (useLds) {
                // indicator from eb (broadcast LDS reads)
                #pragma unroll
                for (int j = 0; j < 4; ++j) {
                    int idx = lb + q * 4 + j;
                    int dl = (b0 + q * 4 + j < s1) ? (int)(eb[min(idx, nstm1)] >> 20) : 31;
                    a2[j] = (dl == c) ? (short)0x3F80 : (short)0;
                }
                if (hasB) {
                    #pragma unroll
                    for (int j = 0; j < 4; ++j) {
                        int idx = lb + 16 + q * 4 + j;
                        int dl = (b0 + 16 + q * 4 + j < s1) ? (int)(eb[min(idx, nstm1)] >> 20) : 31;
                        a2[j + 4] = (dl == c) ? (short)0x3F80 : (short)0;
                    }
                } else {
                    #pragma unroll
                    for (int j = 0; j < 4; ++j) a2[j + 4] = 0;
                }
                // A-frags from staged LDS (one b128 each)
                const unsigned short* rbA = xs + min(lb + c, nstm1) * 72 + q * 16;
                aA0 = *(const s16x8*)(rbA);
                aA1 = *(const s16x8*)(rbA + 8);
                if (hasB) {
                    const unsigned short* rbB = xs + min(lb + 16 + c, nstm1) * 72 + q * 16;
                    aB0 = *(const s16x8*)(rbB);
                    aB1 = *(const s16x8*)(rbB + 8);
                }
            } else {
                // global fallback (rare large tiles)
                int eA = min(b0 + c, s1 - 1);
                unsigned int wa = ep[eA];
                int srcA = (int)(wa & 0xFFFFF);
                int dlA  = (b0 + c < s1) ? (int)(wa >> 20) : 31;
                int srcB = srcA, dlB = 31;
                if (hasB) {
                    int eB = min(b0 + 16 + c, s1 - 1);
                    unsigned int wb = ep[eB];
                    srcB = (int)(wb & 0xFFFFF);
                    dlB  = (b0 + 16 + c < s1) ? (int)(wb >> 20) : 31;
                }
                const unsigned short* xrA = xb + (size_t)srcA * DD + q * 8;
                aA0 = *(const s16x8*)(xrA);
                aA1 = *(const s16x8*)(xrA + 32);
                if (hasB) {
                    const unsigned short* xrB = xb + (size_t)srcB * DD + q * 8;
                    aB0 = *(const s16x8*)(xrB);
                    aB1 = *(const s16x8*)(xrB + 32);
                }
                #pragma unroll
                for (int j = 0; j < 4; ++j) {
                    int dj = __shfl(dlA, q * 4 + j, 64);
                    a2[j] = (dj == c) ? (short)0x3F80 : (short)0;
                }
                #pragma unroll
                for (int j = 0; j < 4; ++j) {
                    int dj = hasB ? __shfl(dlB, q * 4 + j, 64) : 31;
                    a2[j + 4] = (dj == c) ? (short)0x3F80 : (short)0;
                }
            }

            f32x4 cA = {0.f, 0.f, 0.f, 0.f};
            cA = __builtin_amdgcn_mfma_f32_16x16x32_bf16(aA0, w0, cA, 0, 0, 0);
            cA = __builtin_amdgcn_mfma_f32_16x16x32_bf16(aA1, w1, cA, 0, 0, 0);
            s16x8 b2;
            if (hasB) {
                f32x4 cB = {0.f, 0.f, 0.f, 0.f};
                cB = __builtin_amdgcn_mfma_f32_16x16x32_bf16(aB0, w0, cB, 0, 0, 0);
                cB = __builtin_amdgcn_mfma_f32_16x16x32_bf16(aB1, w1, cB, 0, 0, 0);
                #pragma unroll
                for (int j = 0; j < 4; ++j) {
                    b2[j]     = (short)f2bf(cA[j]);
                    b2[j + 4] = (short)f2bf(cB[j]);
                }
            } else {
                #pragma unroll
                for (int j = 0; j < 4; ++j) {
                    b2[j]     = (short)f2bf(cA[j]);
                    b2[j + 4] = 0;
                }
            }
            D = __builtin_amdgcn_mfma_f32_16x16x32_bf16(a2, b2, D, 0, 0, 0);
        }
    }

    // self plane (r==16): A rows = x of this tile (global, contiguous 2KB)
    {
        const unsigned short* wrow = wt + 16 * (DD * DD) + (wid * 16 + c) * DD + q * 8;
        s16x8 w0 = *(const s16x8*)(wrow);
        s16x8 w1 = *(const s16x8*)(wrow + 32);
        const unsigned short* xr = xb + (size_t)(n0 + c) * DD + q * 8;
        s16x8 a0 = *(const s16x8*)(xr);
        s16x8 a1 = *(const s16x8*)(xr + 32);
        f32x4 cA = {0.f, 0.f, 0.f, 0.f};
        cA = __builtin_amdgcn_mfma_f32_16x16x32_bf16(a0, w0, cA, 0, 0, 0);
        cA = __builtin_amdgcn_mfma_f32_16x16x32_bf16(a1, w1, cA, 0, 0, 0);
        s16x8 b2;
        s16x8 a2;
        #pragma unroll
        for (int j = 0; j < 4; ++j) {
            b2[j]     = (short)f2bf(cA[j]);
            b2[j + 4] = 0;
            a2[j]     = (q * 4 + j == c) ? (short)0x3F80 : (short)0;
            a2[j + 4] = 0;
        }
        D = __builtin_amdgcn_mfma_f32_16x16x32_bf16(a2, b2, D, 0, 0, 0);
    }

    // epilogue: D reg v -> node q*4+v, ch wid*16+c ; through padded LDS
    #pragma unroll
    for (int v = 0; v < 4; ++v)
        osg[(q * 4 + v) * 65 + wid * 16 + c] = D[v];
    __syncthreads();

    {
        const int j0 = tid * 4;                  // 1024 outputs / 256 threads
        const int node = j0 >> 6;
        const int ch = j0 & 63;
        float v0 = osg[node * 65 + ch];
        float v1 = osg[node * 65 + ch + 1];
        float v2 = osg[node * 65 + ch + 2];
        float v3 = osg[node * 65 + ch + 3];
        const float4 bv = *(const float4*)(bias + ch);
        v0 += bv.x; v1 += bv.y; v2 += bv.z; v3 += bv.w;
        if (xres) {
            const float4 rv = *(const float4*)(xres + (size_t)(n0 + node) * DD + ch);
            v0 += rv.x; v1 += rv.y; v2 += rv.z; v3 += rv.w;
        }
        v0 = fmaxf(v0, 0.f); v1 = fmaxf(v1, 0.f);
        v2 = fmaxf(v2, 0.f); v3 = fmaxf(v3, 0.f);
        if (outb) {
            uint2 pk;
            pk.x = pack2(v0, v1);
            pk.y = pack2(v2, v3);
            *(uint2*)(outb + (size_t)(n0 + node) * DD + ch) = pk;
        }
        if (outf) {
            float4 o = {v0, v1, v2, v3};
            *(float4*)(outf + (size_t)(n0 + node) * DD + ch) = o;
        }
    }
}

// ================= launch =================

extern "C" void kernel_launch(void* const* d_in, const int* in_sizes, int n_in,
                              void* d_out, int out_size, void* d_ws, size_t ws_size,
                              hipStream_t stream)
{
    (void)in_sizes; (void)n_in; (void)out_size; (void)ws_size;
    const float* x    = (const float*)d_in[0];
    const int*   ei   = (const int*)d_in[1];
    const int*   et   = (const int*)d_in[2];
    const float* W1   = (const float*)d_in[3];
    const float* sw1  = (const float*)d_in[4];
    const float* b1   = (const float*)d_in[5];
    const float* W2   = (const float*)d_in[6];
    const float* sw2  = (const float*)d_in[7];
    const float* b2   = (const float*)d_in[8];
    float* out = (float*)d_out;

    const int* srcA = ei;
    const int* dstA = ei + NE;

    char* ws = (char*)d_ws;
    unsigned short* xb   = (unsigned short*)(ws);                 // 12,800,000
    unsigned short* h1b  = (unsigned short*)(ws + 12800000);      // 12,800,000
    unsigned short* wt2  = (unsigned short*)(ws + 25600000);      //    278,528
    unsigned int*   ep   = (unsigned int*)(ws + 25878528);        //  5,000,000
    int*            rp   = (int*)(ws + 30878528);                 //    400,004
    int*            cnt  = (int*)(ws + 31278544);                 //    400,000
    int*            cur  = (int*)(ws + 31678544);                 //    400,000
    int*            part = (int*)(ws + 32078544);                 //      1,600

    const int NB_E    = (NE + 255) / 256;        // 4883
    const int NB_ELEM = (NN * DD + 255) / 256;   // 25000
    const int WPL = 17 * DD * DD;                // wt2 per-layer stride

    // sort edges by (dst-tile, rel) — once, reused by both layers
    hipMemsetAsync(cnt, 0, NBINS * sizeof(int), stream);
    hist_key<<<NB_E, 256, 0, stream>>>(dstA, et, cnt);
    scan1<<<NBLK_SCAN, 256, 0, stream>>>(cnt, rp, part);
    scan2<<<1, 512, 0, stream>>>(part, rp);
    scan3<<<NBLK_SCAN, 256, 0, stream>>>(rp, part, cur);
    scatter_key<<<NB_E, 256, 0, stream>>>(srcA, dstA, et, cur, ep);

    // precision prep
    prep_w2<<<(2 * 17 * DD * DD + 255) / 256, 256, 0, stream>>>(W1, sw1, W2, sw2, wt2);
    prep_x2<<<NB_ELEM, 256, 0, stream>>>(x, xb);

    // ---- layer 1 (residual) ----
    fused_layer<<<NTILE, 256, 0, stream>>>(xb, wt2, rp, ep, b1, x, h1b, nullptr);
    // ---- layer 2 (no residual) ----
    fused_layer<<<NTILE, 256, 0, stream>>>(h1b, wt2 + WPL, rp, ep, b2, nullptr, nullptr, out);
}

// Round 13
// 530.001 us; speedup vs baseline: 1.0116x; 1.0116x over previous
//
#include <hip/hip_runtime.h>
#include <hip/hip_bf16.h>

#define NN 100000
#define NE 1250000
#define DD 64
#define RR 16
#define NTILE 6250        // NN/16 dst-tiles
#define NBINS 100000      // (dst>>4)*16 + rel
#define NBLK_SCAN 391     // ceil(NBINS/256)
#define EBCAP 512
#define CLCAP 24          // per-wave chunk list cap (cnt<=512 -> <=20 chunks/wave)

typedef __attribute__((ext_vector_type(8))) short s16x8;
typedef __attribute__((ext_vector_type(4))) float f32x4;

static __device__ __forceinline__ unsigned short f2bf(float v) {
    __hip_bfloat16 h = __float2bfloat16(v);
    return __builtin_bit_cast(unsigned short, h);
}
static __device__ __forceinline__ unsigned int pack2(float a, float b) {
    return ((unsigned int)f2bf(b) << 16) | (unsigned int)f2bf(a);
}

// ---------------- sort edges by (dst-tile, rel): counting sort, 100k bins ----------------

__global__ void hist_key(const int* __restrict__ dst, const int* __restrict__ et,
                         int* __restrict__ cnt) {
    int e = blockIdx.x * 256 + threadIdx.x;
    if (e < NE) atomicAdd(&cnt[(dst[e] >> 4) * 16 + et[e]], 1);
}

__global__ __launch_bounds__(256) void scan1(const int* __restrict__ cnt,
                                             int* __restrict__ rp, int* __restrict__ part) {
    __shared__ int s[256];
    int i = blockIdx.x * 256 + threadIdx.x;
    int v = (i < NBINS) ? cnt[i] : 0;
    s[threadIdx.x] = v;
    __syncthreads();
    for (int off = 1; off < 256; off <<= 1) {
        int t = (threadIdx.x >= off) ? s[threadIdx.x - off] : 0;
        __syncthreads();
        s[threadIdx.x] += t;
        __syncthreads();
    }
    if (i < NBINS) rp[i] = s[threadIdx.x] - v;        // exclusive
    if (threadIdx.x == 255) part[blockIdx.x] = s[255];
}

__global__ void scan2(int* __restrict__ part, int* __restrict__ rp) {
    __shared__ int s[NBLK_SCAN];
    if (threadIdx.x < NBLK_SCAN) s[threadIdx.x] = part[threadIdx.x];
    __syncthreads();
    if (threadIdx.x == 0) {
        int acc = 0;
        for (int b = 0; b < NBLK_SCAN; ++b) { int t = s[b]; s[b] = acc; acc += t; }
        rp[NBINS] = NE;
    }
    __syncthreads();
    if (threadIdx.x < NBLK_SCAN) part[threadIdx.x] = s[threadIdx.x];
}

__global__ void scan3(int* __restrict__ rp, const int* __restrict__ part, int* __restrict__ cur) {
    int i = blockIdx.x * 256 + threadIdx.x;
    if (i < NBINS) {
        int v = rp[i] + part[blockIdx.x];
        rp[i] = v;
        cur[i] = v;
    }
}

// ep[p] = src | (dst&15)<<20
__global__ void scatter_key(const int* __restrict__ src, const int* __restrict__ dst,
                            const int* __restrict__ et, int* __restrict__ cur,
                            unsigned int* __restrict__ ep) {
    int e = blockIdx.x * 256 + threadIdx.x;
    if (e >= NE) return;
    int d = dst[e];
    int p = atomicAdd(&cur[(d >> 4) * 16 + et[e]], 1);
    ep[p] = (unsigned int)src[e] | ((unsigned int)(d & 15) << 20);
}

// ---------------- precision prep ----------------

__global__ void prep_w2(const float* __restrict__ W1, const float* __restrict__ sw1,
                        const float* __restrict__ W2, const float* __restrict__ sw2,
                        unsigned short* __restrict__ wt) {
    int i = blockIdx.x * 256 + threadIdx.x;
    if (i >= 2 * 17 * DD * DD) return;
    int d = i & 63;
    int o = (i >> 6) & 63;
    int p = (i >> 12) % 17;
    int l = i / (17 * DD * DD);
    const float* srcp;
    if (p < 16) srcp = (l ? W2 : W1) + p * DD * DD;
    else        srcp = (l ? sw2 : sw1);
    wt[i] = f2bf(srcp[d * DD + o]);
}

__global__ void prep_x2(const float* __restrict__ x, unsigned short* __restrict__ xb) {
    int i = blockIdx.x * blockDim.x + threadIdx.x;
    if (i < NN * DD) xb[i] = f2bf(x[i]);
}

// ---------------- fused layer helpers ----------------

static __device__ __forceinline__ void load_chunk(
    const unsigned short* __restrict__ xb,
    const unsigned int* __restrict__ esrc, int ebase,
    int b0, int s1, int c, int q,
    s16x8& aA0, s16x8& aA1, s16x8& aB0, s16x8& aB1,
    int& dlA, int& dlB, bool& hasB)
{
    hasB = (s1 - b0) > 16;
    int eA = min(b0 + c, s1 - 1);
    unsigned int wa = esrc[eA - ebase];
    int srcA = (int)(wa & 0xFFFFF);
    dlA = (b0 + c < s1) ? (int)(wa >> 20) : 31;
    const unsigned short* xrA = xb + (size_t)srcA * DD + q * 8;
    aA0 = *(const s16x8*)(xrA);
    aA1 = *(const s16x8*)(xrA + 32);
    dlB = 31;
    if (hasB) {
        int eB = min(b0 + 16 + c, s1 - 1);
        unsigned int wb = esrc[eB - ebase];
        int srcB = (int)(wb & 0xFFFFF);
        dlB = (b0 + 16 + c < s1) ? (int)(wb >> 20) : 31;
        const unsigned short* xrB = xb + (size_t)srcB * DD + q * 8;
        aB0 = *(const s16x8*)(xrB);
        aB1 = *(const s16x8*)(xrB + 32);
    } else {
        aB0 = aA0;
        aB1 = aA1;
    }
}

// one 32-edge chunk, all 4 o-blocks into D[4] (R10-verified math)
static __device__ __forceinline__ void compute_chunk4(
    const unsigned short* __restrict__ wt, int r, int c, int q,
    const s16x8& aA0, const s16x8& aA1, const s16x8& aB0, const s16x8& aB1,
    int dlA, int dlB, bool hasB, f32x4* D)
{
    s16x8 a2;
    #pragma unroll
    for (int j = 0; j < 4; ++j) {
        int dj = __shfl(dlA, q * 4 + j, 64);
        a2[j] = (dj == c) ? (short)0x3F80 : (short)0;
    }
    #pragma unroll
    for (int j = 0; j < 4; ++j) {
        int dj = hasB ? __shfl(dlB, q * 4 + j, 64) : 31;
        a2[j + 4] = (dj == c) ? (short)0x3F80 : (short)0;
    }
    #pragma unroll
    for (int ob = 0; ob < 4; ++ob) {
        const unsigned short* wrow = wt + r * (DD * DD) + (ob * 16 + c) * DD + q * 8;
        s16x8 w0 = *(const s16x8*)(wrow);
        s16x8 w1 = *(const s16x8*)(wrow + 32);
        f32x4 cA = {0.f, 0.f, 0.f, 0.f};
        cA = __builtin_amdgcn_mfma_f32_16x16x32_bf16(aA0, w0, cA, 0, 0, 0);
        cA = __builtin_amdgcn_mfma_f32_16x16x32_bf16(aA1, w1, cA, 0, 0, 0);
        s16x8 b2;
        if (hasB) {
            f32x4 cB = {0.f, 0.f, 0.f, 0.f};
            cB = __builtin_amdgcn_mfma_f32_16x16x32_bf16(aB0, w0, cB, 0, 0, 0);
            cB = __builtin_amdgcn_mfma_f32_16x16x32_bf16(aB1, w1, cB, 0, 0, 0);
            #pragma unroll
            for (int j = 0; j < 4; ++j) {
                b2[j]     = (short)f2bf(cA[j]);
                b2[j + 4] = (short)f2bf(cB[j]);
            }
        } else {
            #pragma unroll
            for (int j = 0; j < 4; ++j) {
                b2[j]     = (short)f2bf(cA[j]);
                b2[j + 4] = 0;
            }
        }
        D[ob] = __builtin_amdgcn_mfma_f32_16x16x32_bf16(a2, b2, D[ob], 0, 0, 0);
    }
}

// ---------------- fused layer: R10 math + depth-2 chunk pipeline ----------------
// Block = 16-dst tile. Wave w owns rels {w, w+4, w+8, w+12} (+self on wave 0),
// computing all 64 channels (D[4]); partials summed across waves in LDS.
// Chunk list flattened per wave (built by lane 0, then __syncthreads) and
// processed with a rotate pipeline: chunk i+1's gathers issue before chunk i's
// MFMAs.
__global__ __launch_bounds__(256) void fused_layer(
    const unsigned short* __restrict__ xb,   // [N][64] bf16 layer input
    const unsigned short* __restrict__ wt,   // [17][64][64] bf16 (o-major, d inner)
    const int* __restrict__ rp,              // [NBINS+1]
    const unsigned int* __restrict__ ep,     // [E] src | dstloc<<20
    const float* __restrict__ bias,
    const float* __restrict__ xres,          // fp32 residual or nullptr
    unsigned short* __restrict__ outb,       // bf16 out (layer 1) or nullptr
    float* __restrict__ outf)                // fp32 out (layer 2) or nullptr
{
    __shared__ unsigned int eb[EBCAP];       // 2 KB staged edge words
    __shared__ int rps[17];
    __shared__ float Dred[4 * 1024];         // 16 KB partial-D
    __shared__ int clist[4][CLCAP];
    __shared__ int cmeta[4][3];              // m, ovr_rel, ovr_b0
    const int tid  = threadIdx.x;
    const int wid  = tid >> 6;
    const int lane = tid & 63;
    const int c = lane & 15;
    const int q = lane >> 4;
    const int tile = blockIdx.x;
    const int n0 = tile * 16;

    const int e0 = rp[tile * 16];
    const int cnt = rp[tile * 16 + 16] - e0;
    if (tid < 17) rps[tid] = rp[tile * 16 + tid];
    const bool inLds = (cnt <= EBCAP);
    {
        const int nst = min(cnt, EBCAP);
        for (int i = tid; i < nst; i += 256) eb[i] = ep[e0 + i];
    }
    __syncthreads();

    // build per-wave flattened chunk list (lane 0)
    if (lane == 0) {
        int m = 0;
        int ovr = -1, ovb = 0;
        for (int rr = wid; rr < 16 && ovr < 0; rr += 4) {
            for (int b0 = rps[rr]; b0 < rps[rr + 1]; b0 += 32) {
                if (m < CLCAP) clist[wid][m++] = (rr << 27) | (b0 - e0);
                else { ovr = rr; ovb = b0; break; }
            }
        }
        cmeta[wid][0] = m;
        cmeta[wid][1] = ovr;
        cmeta[wid][2] = ovb;
    }
    __syncthreads();   // clist/cmeta visible to the whole block

    const unsigned int* esrc = inLds ? eb : (ep + e0);   // indexed by (e - e0)
    f32x4 D[4];
    #pragma unroll
    for (int ob = 0; ob < 4; ++ob) D[ob] = (f32x4){0.f, 0.f, 0.f, 0.f};
    const int m = cmeta[wid][0];

    // rotate pipeline over the wave's chunk list
    s16x8 aA0, aA1, aB0, aB1;
    int dlA = 31, dlB = 31;
    bool hB = false;
    int rC = 0;
    if (m > 0) {
        int meta = clist[wid][0];
        rC = meta >> 27;
        int b0 = e0 + (meta & 0x7FFFFFF);
        load_chunk(xb, esrc, e0, b0, rps[rC + 1], c, q, aA0, aA1, aB0, aB1, dlA, dlB, hB);
    }
    for (int ci = 0; ci < m; ++ci) {
        s16x8 nA0, nA1, nB0, nB1;
        int ndlA = 31, ndlB = 31;
        bool nhB = false;
        int rN = 0;
        if (ci + 1 < m) {
            int meta = clist[wid][ci + 1];
            rN = meta >> 27;
            int b0 = e0 + (meta & 0x7FFFFFF);
            load_chunk(xb, esrc, e0, b0, rps[rN + 1], c, q, nA0, nA1, nB0, nB1, ndlA, ndlB, nhB);
        }
        compute_chunk4(wt, rC, c, q, aA0, aA1, aB0, aB1, dlA, dlB, hB, D);
        aA0 = nA0; aA1 = nA1; aB0 = nB0; aB1 = nB1;
        dlA = ndlA; dlB = ndlB; hB = nhB; rC = rN;
    }

    // overflow remainder (very large tiles only): serial chunks
    {
        const int orr = cmeta[wid][1];
        if (orr >= 0) {
            for (int rr = orr; rr < 16; rr += 4) {
                const int bst = (rr == orr) ? cmeta[wid][2] : rps[rr];
                const int s1 = rps[rr + 1];
                for (int b0 = bst; b0 < s1; b0 += 32) {
                    s16x8 tA0, tA1, tB0, tB1;
                    int tdlA, tdlB;
                    bool thB;
                    load_chunk(xb, esrc, e0, b0, s1, c, q, tA0, tA1, tB0, tB1, tdlA, tdlB, thB);
                    compute_chunk4(wt, rr, c, q, tA0, tA1, tB0, tB1, tdlA, tdlB, thB, D);
                }
            }
        }
    }

    // self plane (wave 0 only; rows = x of this tile, identity indicator)
    if (wid == 0) {
        const unsigned short* xr = xb + (size_t)(n0 + c) * DD + q * 8;
        s16x8 a0 = *(const s16x8*)(xr);
        s16x8 a1 = *(const s16x8*)(xr + 32);
        s16x8 a2;
        #pragma unroll
        for (int j = 0; j < 4; ++j) {
            a2[j]     = (q * 4 + j == c) ? (short)0x3F80 : (short)0;
            a2[j + 4] = 0;
        }
        #pragma unroll
        for (int ob = 0; ob < 4; ++ob) {
            const unsigned short* wrow = wt + 16 * (DD * DD) + (ob * 16 + c) * DD + q * 8;
            s16x8 w0 = *(const s16x8*)(wrow);
            s16x8 w1 = *(const s16x8*)(wrow + 32);
            f32x4 cA = {0.f, 0.f, 0.f, 0.f};
            cA = __builtin_amdgcn_mfma_f32_16x16x32_bf16(a0, w0, cA, 0, 0, 0);
            cA = __builtin_amdgcn_mfma_f32_16x16x32_bf16(a1, w1, cA, 0, 0, 0);
            s16x8 b2;
            #pragma unroll
            for (int j = 0; j < 4; ++j) {
                b2[j]     = (short)f2bf(cA[j]);
                b2[j + 4] = 0;
            }
            D[ob] = __builtin_amdgcn_mfma_f32_16x16x32_bf16(a2, b2, D[ob], 0, 0, 0);
        }
    }

    // stage partial D: Dred[wid][node*64 + ch]
    {
        float* dred = Dred + wid * 1024;
        #pragma unroll
        for (int ob = 0; ob < 4; ++ob)
            #pragma unroll
            for (int v = 0; v < 4; ++v)
                dred[(q * 4 + v) * 64 + ob * 16 + c] = D[ob][v];
    }
    __syncthreads();

    // reduce 4 partials + bias (+res) + relu; coalesced stores
    #pragma unroll
    for (int k = 0; k < 2; ++k) {
        int j = k * 512 + tid * 2;
        int node = j >> 6, ch = j & 63;
        float v0 = Dred[j]        + Dred[1024 + j]     + Dred[2048 + j]     + Dred[3072 + j];
        float v1 = Dred[j + 1]    + Dred[1024 + j + 1] + Dred[2048 + j + 1] + Dred[3072 + j + 1];
        v0 += bias[ch];
        v1 += bias[ch + 1];
        if (xres) {
            const float2 rv = *(const float2*)(xres + (size_t)(n0 + node) * DD + ch);
            v0 += rv.x; v1 += rv.y;
        }
        v0 = fmaxf(v0, 0.f);
        v1 = fmaxf(v1, 0.f);
        if (outb)
            *(unsigned int*)(outb + (size_t)(n0 + node) * DD + ch) = pack2(v0, v1);
        if (outf) {
            float2 o = {v0, v1};
            *(float2*)(outf + (size_t)(n0 + node) * DD + ch) = o;
        }
    }
}

// ================= launch =================

extern "C" void kernel_launch(void* const* d_in, const int* in_sizes, int n_in,
                              void* d_out, int out_size, void* d_ws, size_t ws_size,
                              hipStream_t stream)
{
    (void)in_sizes; (void)n_in; (void)out_size; (void)ws_size;
    const float* x    = (const float*)d_in[0];
    const int*   ei   = (const int*)d_in[1];
    const int*   et   = (const int*)d_in[2];
    const float* W1   = (const float*)d_in[3];
    const float* sw1  = (const float*)d_in[4];
    const float* b1   = (const float*)d_in[5];
    const float* W2   = (const float*)d_in[6];
    const float* sw2  = (const float*)d_in[7];
    const float* b2   = (const float*)d_in[8];
    float* out = (float*)d_out;

    const int* srcA = ei;
    const int* dstA = ei + NE;

    char* ws = (char*)d_ws;
    unsigned short* xb   = (unsigned short*)(ws);                 // 12,800,000
    unsigned short* h1b  = (unsigned short*)(ws + 12800000);      // 12,800,000
    unsigned short* wt2  = (unsigned short*)(ws + 25600000);      //    278,528
    unsigned int*   ep   = (unsigned int*)(ws + 25878528);        //  5,000,000
    int*            rp   = (int*)(ws + 30878528);                 //    400,004
    int*            cnt  = (int*)(ws + 31278544);                 //    400,000
    int*            cur  = (int*)(ws + 31678544);                 //    400,000
    int*            part = (int*)(ws + 32078544);                 //      1,600

    const int NB_E    = (NE + 255) / 256;        // 4883
    const int NB_ELEM = (NN * DD + 255) / 256;   // 25000
    const int WPL = 17 * DD * DD;                // wt2 per-layer stride

    // sort edges by (dst-tile, rel) — once, reused by both layers
    hipMemsetAsync(cnt, 0, NBINS * sizeof(int), stream);
    hist_key<<<NB_E, 256, 0, stream>>>(dstA, et, cnt);
    scan1<<<NBLK_SCAN, 256, 0, stream>>>(cnt, rp, part);
    scan2<<<1, 512, 0, stream>>>(part, rp);
    scan3<<<NBLK_SCAN, 256, 0, stream>>>(rp, part, cur);
    scatter_key<<<NB_E, 256, 0, stream>>>(srcA, dstA, et, cur, ep);

    // precision prep
    prep_w2<<<(2 * 17 * DD * DD + 255) / 256, 256, 0, stream>>>(W1, sw1, W2, sw2, wt2);
    prep_x2<<<NB_ELEM, 256, 0, stream>>>(x, xb);

    // ---- layer 1 (residual) ----
    fused_layer<<<NTILE, 256, 0, stream>>>(xb, wt2, rp, ep, b1, x, h1b, nullptr);
    // ---- layer 2 (no residual) ----
    fused_layer<<<NTILE, 256, 0, stream>>>(h1b, wt2 + WPL, rp, ep, b2, nullptr, nullptr, out);
}